// Round 4
// baseline (83.893 us; speedup 1.0000x reference)
//
#include <hip/hip_runtime.h>

#define KN 8192

// Monotone float -> uint32 transform (order-preserving), packed with the
// element index into a distinct 64-bit key. Lexicographic (value, index)
// order == jnp stable argsort order. index < 8192 = 2^13.
// 64-bit is REQUIRED: expected float32 collisions among 8192 N(0,1) samples
// is ~1 (birthday), so value-only ranks would break the scatter.
__device__ __forceinline__ unsigned long long make_key(float x, int idx) {
    unsigned int u = __float_as_uint(x);
    u ^= (unsigned int)((int)u >> 31) | 0x80000000u;  // neg: flip all; pos: set sign
    return ((unsigned long long)u << 13) | (unsigned int)idx;
}

// ---------------------------------------------------------------------------
// K1: partial ranks, brute force, NO atomics.
// rank[u] = #{ v : key[v] < key[u] }  (keys distinct)
// grid = 8 u-tiles x 64 v-tiles x 2 arrays = 1024 blocks of 256 threads.
// Per block: 1024 u (4/thread) x 128 v.
// part[(arr*NVT + vt)*KN + u] -- disjoint slice per block, coalesced stores.
// ---------------------------------------------------------------------------
constexpr int UT  = 1024;
constexpr int VC  = 128;
constexpr int NVT = KN / VC;     // 64

__global__ __launch_bounds__(256) void rank_partial(const float* __restrict__ X,
                                                    const float* __restrict__ Xh,
                                                    int* __restrict__ part) {
    int blk = blockIdx.x;
    int arr = blk & 1;
    int vt  = (blk >> 1) & (NVT - 1);
    int ut  = blk >> 7;
    const float* src = arr ? Xh : X;

    int tid = threadIdx.x;
    int u0 = ut * UT + tid;

    unsigned long long ku0 = make_key(src[u0],       u0);
    unsigned long long ku1 = make_key(src[u0 + 256], u0 + 256);
    unsigned long long ku2 = make_key(src[u0 + 512], u0 + 512);
    unsigned long long ku3 = make_key(src[u0 + 768], u0 + 768);

    __shared__ unsigned long long tile[VC];
    if (tid < VC) {
        int v = vt * VC + tid;
        tile[tid] = make_key(src[v], v);
    }
    __syncthreads();

    int c0 = 0, c1 = 0, c2 = 0, c3 = 0;
#pragma unroll 8
    for (int jj = 0; jj < VC; ++jj) {
        unsigned long long kv = tile[jj];   // wave-uniform -> LDS broadcast
        c0 += (kv < ku0);
        c1 += (kv < ku1);
        c2 += (kv < ku2);
        c3 += (kv < ku3);
    }

    int base = (arr * NVT + vt) * KN + u0;
    part[base]       = c0;
    part[base + 256] = c1;
    part[base + 512] = c2;
    part[base + 768] = c3;
}

// ---------------------------------------------------------------------------
// K2: reduce partials. arr0 -> store rank_a[u]; arr1 -> scatter b[r] = u.
// Also zeroes count/ticket for K3 (stream order guarantees visibility).
// grid = 64 blocks x 256  (threads 0..8191 -> rank_a, 8192..16383 -> b)
// ---------------------------------------------------------------------------
__global__ __launch_bounds__(256) void reduce_scatter(const int* __restrict__ part,
                                                      int* __restrict__ rank_a,
                                                      int* __restrict__ b,
                                                      unsigned int* __restrict__ count,
                                                      unsigned int* __restrict__ ticket) {
    if (blockIdx.x == 0 && threadIdx.x == 0) { *count = 0u; *ticket = 0u; }

    int t = blockIdx.x * 256 + threadIdx.x;   // 0..16383
    int arr = t >> 13;
    int u   = t & (KN - 1);

    const int* p = part + (arr * NVT) * KN + u;
    int r = 0;
#pragma unroll 8
    for (int vt = 0; vt < NVT; ++vt) r += p[vt * KN];   // coalesced across threads

    if (arr == 0) rank_a[u] = r;
    else          b[r] = u;
}

// ---------------------------------------------------------------------------
// K3: inversion count of e[k] = b[rank_a[k]] (e gathered on the fly; the 'a'
// array and a separate gather kernel are unnecessary since a[rank_a[k]]=k).
// Triangular 256-tiles: 32*33/2 = 528 blocks. Off-diag inner op: int4 LDS
// broadcast + 4x(cmp+addc). Last block (ticket) finalizes the output:
// ndisordered = 2*D, out = 2*D / (n*(n-1)).
// ---------------------------------------------------------------------------
__global__ __launch_bounds__(256) void inv_finalize(const int* __restrict__ rank_a,
                                                    const int* __restrict__ b,
                                                    unsigned int* __restrict__ count,
                                                    unsigned int* __restrict__ ticket,
                                                    float* __restrict__ out) {
    constexpr int TS = 256;
    constexpr int T  = KN / TS;   // 32

    int blk = blockIdx.x;
    int p = 0, rem = blk;
    while (rem >= T - p) { rem -= T - p; ++p; }   // wave-uniform decode
    int q = p + rem;                              // p <= q

    __shared__ int le[TS];
    __shared__ int wsum[4];
    int tid = threadIdx.x;

    int ek = b[rank_a[p * TS + tid]];             // e[k], k = p*TS+tid
    le[tid] = b[rank_a[q * TS + tid]];            // e[l], l = q*TS+tid
    __syncthreads();

    int cnt = 0;
    if (p == q) {
        for (int j = tid + 1; j < TS; ++j) cnt += (ek > le[j]);
    } else {
        const int4* le4 = (const int4*)le;
#pragma unroll 8
        for (int j4 = 0; j4 < TS / 4; ++j4) {
            int4 v = le4[j4];                     // wave-uniform -> ds_read_b128
            cnt += (ek > v.x) + (ek > v.y) + (ek > v.z) + (ek > v.w);
        }
    }

    for (int off = 32; off; off >>= 1) cnt += __shfl_down(cnt, off);
    if ((tid & 63) == 0) wsum[tid >> 6] = cnt;
    __syncthreads();

    if (tid == 0) {
        unsigned int blkCnt = (unsigned int)(wsum[0] + wsum[1] + wsum[2] + wsum[3]);
        atomicAdd(count, blkCnt);                 // device-scope
        __threadfence();
        unsigned int done = atomicAdd(ticket, 1u);
        if (done == 527u) {                       // last block: all adds visible
            unsigned int D = atomicAdd(count, 0u);
            out[0] = 2.0f * (float)D / ((float)KN * (float)(KN - 1));
        }
    }
}

// ---------------------------------------------------------------------------
// Workspace layout (bytes). Every word is written before it is read each call
// (count/ticket zeroed by K2), so the harness 0xAA poison needs no memset.
//   0        : part[2*64*8192] int  (4 MiB)
//   4194304  : rank_a[8192] int
//   4227072  : b[8192] int
//   4259840  : count, ticket (uint each)
// ---------------------------------------------------------------------------
extern "C" void kernel_launch(void* const* d_in, const int* in_sizes, int n_in,
                              void* d_out, int out_size, void* d_ws, size_t ws_size,
                              hipStream_t stream) {
    const float* X  = (const float*)d_in[0];
    const float* Xh = (const float*)d_in[1];

    char* ws = (char*)d_ws;
    int* part            = (int*)(ws);
    int* rank_a          = (int*)(ws + 4194304);
    int* b               = (int*)(ws + 4227072);
    unsigned int* count  = (unsigned int*)(ws + 4259840);
    unsigned int* ticket = (unsigned int*)(ws + 4259844);

    rank_partial  <<<dim3(1024), dim3(256), 0, stream>>>(X, Xh, part);
    reduce_scatter<<<dim3(64),   dim3(256), 0, stream>>>(part, rank_a, b, count, ticket);
    inv_finalize  <<<dim3(528),  dim3(256), 0, stream>>>(rank_a, b, count, ticket,
                                                         (float*)d_out);
}